// Round 1
// baseline (3593.229 us; speedup 1.0000x reference)
//
#include <hip/hip_runtime.h>
#include <hip/hip_bf16.h>
#include <math.h>

#define D 256
#define EPS 1e-5f

// ---------------------------------------------------------------- degree
__global__ void k_degree(const int* __restrict__ dst, float* __restrict__ deg, int E) {
    int e = blockIdx.x * blockDim.x + threadIdx.x;
    if (e < E) atomicAdd(&deg[dst[e]], 1.0f);
}

__global__ void k_dinv(float* __restrict__ deg, int N) {
    int i = blockIdx.x * blockDim.x + threadIdx.x;
    if (i < N) deg[i] = rsqrtf(1.0f + deg[i]);
}

// ---------------------------------------------------------------- GEMM: out[N,256] = A[N,K] @ W[K,256]
// one block = 8 rows, 256 threads = 256 output columns
#define GROWS 8
#define LDS_STRIDE 12   // 8 floats used, padded to 12 for 16B-aligned float4 reads
__global__ void k_gemm(const float* __restrict__ A, const float* __restrict__ W,
                       float* __restrict__ out, int N, int K) {
    __shared__ __align__(16) float lds[256 * LDS_STRIDE];
    int i0 = blockIdx.x * GROWS;
    int rows = N - i0; if (rows > GROWS) rows = GROWS;

    for (int idx = threadIdx.x; idx < rows * K; idx += 256) {
        int r = idx / K;
        int k = idx - r * K;
        lds[k * LDS_STRIDE + r] = A[(size_t)(i0 + r) * K + k];
    }
    // zero-fill tail rows so FMAs don't ingest NaN garbage
    if (rows < GROWS) {
        for (int idx = threadIdx.x; idx < GROWS * K; idx += 256) {
            int r = idx / K;
            int k = idx - r * K;
            if (r >= rows) lds[k * LDS_STRIDE + r] = 0.0f;
        }
    }
    __syncthreads();

    int d = threadIdx.x;
    float acc[GROWS];
#pragma unroll
    for (int r = 0; r < GROWS; ++r) acc[r] = 0.0f;

    for (int k = 0; k < K; ++k) {
        float w = W[(size_t)k * D + d];
        const float4* a4 = (const float4*)&lds[k * LDS_STRIDE];
        float4 a0 = a4[0];
        float4 a1 = a4[1];
        acc[0] = fmaf(a0.x, w, acc[0]);
        acc[1] = fmaf(a0.y, w, acc[1]);
        acc[2] = fmaf(a0.z, w, acc[2]);
        acc[3] = fmaf(a0.w, w, acc[3]);
        acc[4] = fmaf(a1.x, w, acc[4]);
        acc[5] = fmaf(a1.y, w, acc[5]);
        acc[6] = fmaf(a1.z, w, acc[6]);
        acc[7] = fmaf(a1.w, w, acc[7]);
    }
    for (int r = 0; r < rows; ++r) out[(size_t)(i0 + r) * D + d] = acc[r];
}

// ---------------------------------------------------------------- edge scatter: agg[dst] += hw[src] * dinv[src]*dinv[dst]
__global__ void k_scatter(const int* __restrict__ src, const int* __restrict__ dst,
                          const float* __restrict__ hw, const float* __restrict__ dinv,
                          float* __restrict__ agg, int E) {
    int e = blockIdx.x;
    int d = threadIdx.x;
    int s = src[e];
    int t = dst[e];
    float c = dinv[s] * dinv[t];
    atomicAdd(&agg[(size_t)t * D + d], hw[(size_t)s * D + d] * c);
}

// ---------------------------------------------------------------- self-loop + bias + BN stats
// agg <- agg + hw*dinv^2 + b ; accumulate per-feature sum & sumsq
__global__ void k_selfloop_stats(float* __restrict__ agg, const float* __restrict__ hw,
                                 const float* __restrict__ dinv, const float* __restrict__ b,
                                 float* __restrict__ sums, float* __restrict__ sumsq, int N) {
    int d = threadIdx.x;
    float bd = b[d];
    float s = 0.0f, ss = 0.0f;
    for (int i = blockIdx.x; i < N; i += gridDim.x) {
        float di = dinv[i];
        size_t off = (size_t)i * D + d;
        float v = agg[off] + hw[off] * (di * di) + bd;
        agg[off] = v;
        s += v;
        ss += v * v;
    }
    atomicAdd(&sums[d], s);
    atomicAdd(&sumsq[d], ss);
}

// sums -> scale, sumsq -> shift
__global__ void k_finalize(float* __restrict__ sums, float* __restrict__ sumsq,
                           const float* __restrict__ g, const float* __restrict__ be,
                           float Ninv) {
    int d = threadIdx.x;
    float mu = sums[d] * Ninv;
    float var = sumsq[d] * Ninv - mu * mu;
    float sc = g[d] * rsqrtf(var + EPS);
    sums[d] = sc;
    sumsq[d] = be[d] - mu * sc;
}

// h <- tanh(h*scale + shift), float4-vectorized; n4 = N*D/4, D/4 == 64
__global__ void k_bn_tanh(float* __restrict__ h, const float* __restrict__ scale,
                          const float* __restrict__ shift, int n4) {
    int i = blockIdx.x * blockDim.x + threadIdx.x;
    if (i >= n4) return;
    float4 v = ((float4*)h)[i];
    int d = (i & 63) * 4;
    v.x = tanhf(fmaf(v.x, scale[d + 0], shift[d + 0]));
    v.y = tanhf(fmaf(v.y, scale[d + 1], shift[d + 1]));
    v.z = tanhf(fmaf(v.z, scale[d + 2], shift[d + 2]));
    v.w = tanhf(fmaf(v.w, scale[d + 3], shift[d + 3]));
    ((float4*)h)[i] = v;
}

// ---------------------------------------------------------------- pooling + output GEMV
__device__ __forceinline__ int lb(const int* __restrict__ a, int n, int v) {
    int lo = 0, hi = n;
    while (lo < hi) {
        int mid = (lo + hi) >> 1;
        if (a[mid] < v) lo = mid + 1; else hi = mid;
    }
    return lo;
}

__global__ void k_pool(const float* __restrict__ h, const int* __restrict__ batch,
                       const float* __restrict__ Wout, const float* __restrict__ bout,
                       float* __restrict__ out, float* __restrict__ hidden, int N) {
    int g = blockIdx.x;
    int d = threadIdx.x;
    int lo = lb(batch, N, g);
    int hi = lb(batch, N, g + 1);
    float mx = -INFINITY, sm = 0.0f;
    for (int i = lo; i < hi; ++i) {
        float v = h[(size_t)i * D + d];
        mx = fmaxf(mx, v);
        sm += v;
    }
    float mean = sm / (float)(hi - lo);
    hidden[(size_t)g * (2 * D) + d] = mx;
    hidden[(size_t)g * (2 * D) + D + d] = mean;

    float p = mx * Wout[d] + mean * Wout[D + d];
    __shared__ float red[256];
    red[d] = p;
    __syncthreads();
    for (int s = 128; s > 0; s >>= 1) {
        if (d < s) red[d] += red[d + s];
        __syncthreads();
    }
    if (d == 0) out[g] = red[0] + bout[0];
}

// ----------------------------------------------------------------
extern "C" void kernel_launch(void* const* d_in, const int* in_sizes, int n_in,
                              void* d_out, int out_size, void* d_ws, size_t ws_size,
                              hipStream_t stream) {
    const float* x          = (const float*)d_in[0];
    const int*   edge_index = (const int*)d_in[1];
    const int*   batch      = (const int*)d_in[2];
    const float* Wl[4] = {(const float*)d_in[4], (const float*)d_in[6],
                          (const float*)d_in[8], (const float*)d_in[10]};
    const float* bl[4] = {(const float*)d_in[5], (const float*)d_in[7],
                          (const float*)d_in[9], (const float*)d_in[11]};
    const float* gl[4]  = {(const float*)d_in[12], (const float*)d_in[14],
                           (const float*)d_in[16], (const float*)d_in[18]};
    const float* bel[4] = {(const float*)d_in[13], (const float*)d_in[15],
                           (const float*)d_in[17], (const float*)d_in[19]};
    const float* Wout = (const float*)d_in[20];
    const float* bout = (const float*)d_in[21];

    const int N = in_sizes[0] / 64;     // 50000
    const int E = in_sizes[1] / 2;      // 800000
    const int B = out_size / (1 + 2 * D); // 1000

    const int* srcv = edge_index;
    const int* dstv = edge_index + E;

    float* P0    = (float*)d_ws;                 // hw  = h_in @ W
    float* P1    = P0 + (size_t)N * D;           // agg / h (ping, reused every layer)
    float* deg   = P1 + (size_t)N * D;           // deg -> dinv in place
    float* sums  = deg + N;                      // -> scale
    float* sumsq = sums + D;                     // -> shift

    float* out_p    = (float*)d_out;             // [B]
    float* hidden_p = out_p + B;                 // [B, 512]

    // degree + dinv
    hipMemsetAsync(deg, 0, (size_t)N * sizeof(float), stream);
    k_degree<<<(E + 255) / 256, 256, 0, stream>>>(dstv, deg, E);
    k_dinv<<<(N + 255) / 256, 256, 0, stream>>>(deg, N);

    const float* hcur = x;
    int K = 64;
    for (int l = 0; l < 4; ++l) {
        k_gemm<<<(N + GROWS - 1) / GROWS, 256, 0, stream>>>(hcur, Wl[l], P0, N, K);
        hipMemsetAsync(P1, 0, (size_t)N * D * sizeof(float), stream);
        hipMemsetAsync(sums, 0, 2 * D * sizeof(float), stream);
        k_scatter<<<E, 256, 0, stream>>>(srcv, dstv, P0, deg, P1, E);
        k_selfloop_stats<<<256, 256, 0, stream>>>(P1, P0, deg, bl[l], sums, sumsq, N);
        k_finalize<<<1, 256, 0, stream>>>(sums, sumsq, gl[l], bel[l], 1.0f / (float)N);
        k_bn_tanh<<<((N * D / 4) + 255) / 256, 256, 0, stream>>>(P1, sums, sumsq, N * D / 4);
        hcur = P1;
        K = D;
    }

    k_pool<<<B, 256, 0, stream>>>(P1, batch, Wout, bout, out_p, hidden_p, N);
}

// Round 2
// 1615.698 us; speedup vs baseline: 2.2239x; 2.2239x over previous
//
#include <hip/hip_runtime.h>
#include <hip/hip_bf16.h>
#include <math.h>

#define D 256
#define EPS 1e-5f

// ---------------------------------------------------------------- CSR build
__global__ void k_count(const int* __restrict__ dst, int* __restrict__ cnt, int E) {
    int e = blockIdx.x * blockDim.x + threadIdx.x;
    if (e < E) atomicAdd(&cnt[dst[e]], 1);
}

__global__ void k_dinv(const int* __restrict__ cnt, float* __restrict__ dinv, int N) {
    int i = blockIdx.x * blockDim.x + threadIdx.x;
    if (i < N) dinv[i] = rsqrtf(1.0f + (float)cnt[i]);
}

// single-block two-pass prefix scan over N counts -> row_ptr[N+1], cursor[N]
__global__ void k_scan(const int* __restrict__ cnt, int* __restrict__ row_ptr,
                       int* __restrict__ cursor, int N) {
    __shared__ int part[257];
    int t = threadIdx.x;                  // 256 threads
    int chunk = (N + 255) / 256;
    int lo = t * chunk;
    int hi = lo + chunk; if (hi > N) hi = N; if (lo > N) lo = N;
    int s = 0;
    for (int i = lo; i < hi; ++i) s += cnt[i];
    part[t + 1] = s;
    if (t == 0) part[0] = 0;
    __syncthreads();
    if (t == 0) {
        for (int i = 1; i <= 256; ++i) part[i] += part[i - 1];
    }
    __syncthreads();
    int run = part[t];
    for (int i = lo; i < hi; ++i) {
        row_ptr[i] = run;
        cursor[i]  = run;
        run += cnt[i];
    }
    if (t == 255) row_ptr[N] = run;
}

__global__ void k_fill(const int* __restrict__ src, const int* __restrict__ dst,
                       const float* __restrict__ dinv, int* __restrict__ cursor,
                       int* __restrict__ col, float* __restrict__ coef, int E) {
    int e = blockIdx.x * blockDim.x + threadIdx.x;
    if (e >= E) return;
    int s = src[e], t = dst[e];
    int slot = atomicAdd(&cursor[t], 1);
    col[slot]  = s;
    coef[slot] = dinv[s] * dinv[t];
}

// ---------------------------------------------------------------- GEMM: out[N,256] = A[N,K] @ W[K,256]
#define GROWS 8
#define LDS_STRIDE 12
__global__ void k_gemm(const float* __restrict__ A, const float* __restrict__ W,
                       float* __restrict__ out, int N, int K) {
    __shared__ __align__(16) float lds[256 * LDS_STRIDE];
    int i0 = blockIdx.x * GROWS;
    int rows = N - i0; if (rows > GROWS) rows = GROWS;

    for (int idx = threadIdx.x; idx < rows * K; idx += 256) {
        int r = idx / K;
        int k = idx - r * K;
        lds[k * LDS_STRIDE + r] = A[(size_t)(i0 + r) * K + k];
    }
    if (rows < GROWS) {
        for (int idx = threadIdx.x; idx < GROWS * K; idx += 256) {
            int r = idx / K;
            int k = idx - r * K;
            if (r >= rows) lds[k * LDS_STRIDE + r] = 0.0f;
        }
    }
    __syncthreads();

    int d = threadIdx.x;
    float acc[GROWS];
#pragma unroll
    for (int r = 0; r < GROWS; ++r) acc[r] = 0.0f;

    for (int k = 0; k < K; ++k) {
        float w = W[(size_t)k * D + d];
        const float4* a4 = (const float4*)&lds[k * LDS_STRIDE];
        float4 a0 = a4[0];
        float4 a1 = a4[1];
        acc[0] = fmaf(a0.x, w, acc[0]);
        acc[1] = fmaf(a0.y, w, acc[1]);
        acc[2] = fmaf(a0.z, w, acc[2]);
        acc[3] = fmaf(a0.w, w, acc[3]);
        acc[4] = fmaf(a1.x, w, acc[4]);
        acc[5] = fmaf(a1.y, w, acc[5]);
        acc[6] = fmaf(a1.z, w, acc[6]);
        acc[7] = fmaf(a1.w, w, acc[7]);
    }
    for (int r = 0; r < rows; ++r) out[(size_t)(i0 + r) * D + d] = acc[r];
}

// ---------------------------------------------------------------- fused gather-aggregate + self-loop + bias + BN stats
// out[i,:] = sum_{e in CSR[i]} hw[col[e],:]*coef[e] + hw[i,:]*dinv[i]^2 + b
// plus per-feature sum/sumsq accumulation (one atomic per block per feature)
__global__ void k_gather(const int* __restrict__ row_ptr, const int* __restrict__ col,
                         const float* __restrict__ coef, const float* __restrict__ hw,
                         const float* __restrict__ dinv, const float* __restrict__ b,
                         float* __restrict__ out, float* __restrict__ sums,
                         float* __restrict__ sumsq, int N) {
    int d = threadIdx.x;
    float bd = b[d];
    float s = 0.0f, ss = 0.0f;
    for (int i = blockIdx.x; i < N; i += gridDim.x) {
        int lo = row_ptr[i];
        int hi = row_ptr[i + 1];
        float di = dinv[i];
        float acc = fmaf(hw[(size_t)i * D + d], di * di, bd);
        for (int e = lo; e < hi; ++e) {
            int sn  = col[e];
            float c = coef[e];
            acc = fmaf(hw[(size_t)sn * D + d], c, acc);
        }
        out[(size_t)i * D + d] = acc;
        s  += acc;
        ss += acc * acc;
    }
    atomicAdd(&sums[d], s);
    atomicAdd(&sumsq[d], ss);
}

// sums -> scale, sumsq -> shift
__global__ void k_finalize(float* __restrict__ sums, float* __restrict__ sumsq,
                           const float* __restrict__ g, const float* __restrict__ be,
                           float Ninv) {
    int d = threadIdx.x;
    float mu = sums[d] * Ninv;
    float var = sumsq[d] * Ninv - mu * mu;
    float sc = g[d] * rsqrtf(var + EPS);
    sums[d] = sc;
    sumsq[d] = be[d] - mu * sc;
}

// h <- tanh(h*scale + shift), float4-vectorized
__global__ void k_bn_tanh(float* __restrict__ h, const float* __restrict__ scale,
                          const float* __restrict__ shift, int n4) {
    int i = blockIdx.x * blockDim.x + threadIdx.x;
    if (i >= n4) return;
    float4 v = ((float4*)h)[i];
    int d = (i & 63) * 4;
    v.x = tanhf(fmaf(v.x, scale[d + 0], shift[d + 0]));
    v.y = tanhf(fmaf(v.y, scale[d + 1], shift[d + 1]));
    v.z = tanhf(fmaf(v.z, scale[d + 2], shift[d + 2]));
    v.w = tanhf(fmaf(v.w, scale[d + 3], shift[d + 3]));
    ((float4*)h)[i] = v;
}

// ---------------------------------------------------------------- pooling + output GEMV
__device__ __forceinline__ int lb(const int* __restrict__ a, int n, int v) {
    int lo = 0, hi = n;
    while (lo < hi) {
        int mid = (lo + hi) >> 1;
        if (a[mid] < v) lo = mid + 1; else hi = mid;
    }
    return lo;
}

__global__ void k_pool(const float* __restrict__ h, const int* __restrict__ batch,
                       const float* __restrict__ Wout, const float* __restrict__ bout,
                       float* __restrict__ out, float* __restrict__ hidden, int N) {
    int g = blockIdx.x;
    int d = threadIdx.x;
    int lo = lb(batch, N, g);
    int hi = lb(batch, N, g + 1);
    float mx = -INFINITY, sm = 0.0f;
    for (int i = lo; i < hi; ++i) {
        float v = h[(size_t)i * D + d];
        mx = fmaxf(mx, v);
        sm += v;
    }
    float mean = sm / (float)(hi - lo);
    hidden[(size_t)g * (2 * D) + d] = mx;
    hidden[(size_t)g * (2 * D) + D + d] = mean;

    float p = mx * Wout[d] + mean * Wout[D + d];
    __shared__ float red[256];
    red[d] = p;
    __syncthreads();
    for (int s = 128; s > 0; s >>= 1) {
        if (d < s) red[d] += red[d + s];
        __syncthreads();
    }
    if (d == 0) out[g] = red[0] + bout[0];
}

// ----------------------------------------------------------------
extern "C" void kernel_launch(void* const* d_in, const int* in_sizes, int n_in,
                              void* d_out, int out_size, void* d_ws, size_t ws_size,
                              hipStream_t stream) {
    const float* x          = (const float*)d_in[0];
    const int*   edge_index = (const int*)d_in[1];
    const int*   batch      = (const int*)d_in[2];
    const float* Wl[4] = {(const float*)d_in[4], (const float*)d_in[6],
                          (const float*)d_in[8], (const float*)d_in[10]};
    const float* bl[4] = {(const float*)d_in[5], (const float*)d_in[7],
                          (const float*)d_in[9], (const float*)d_in[11]};
    const float* gl[4]  = {(const float*)d_in[12], (const float*)d_in[14],
                           (const float*)d_in[16], (const float*)d_in[18]};
    const float* bel[4] = {(const float*)d_in[13], (const float*)d_in[15],
                           (const float*)d_in[17], (const float*)d_in[19]};
    const float* Wout = (const float*)d_in[20];
    const float* bout = (const float*)d_in[21];

    const int N = in_sizes[0] / 64;       // 50000
    const int E = in_sizes[1] / 2;        // 800000
    const int B = out_size / (1 + 2 * D); // 1000

    const int* srcv = edge_index;
    const int* dstv = edge_index + E;

    // workspace carve-up
    float* P0      = (float*)d_ws;              // [N,D] hw = h_in @ W
    float* P1      = P0 + (size_t)N * D;        // [N,D] layer output (ping)
    float* dinv    = P1 + (size_t)N * D;        // [N]
    float* sums    = dinv + N;                  // [D] -> scale
    float* sumsq   = sums + D;                  // [D] -> shift
    float* coef    = sumsq + D;                 // [E]
    int*   cnt     = (int*)(coef + E);          // [N]
    int*   row_ptr = cnt + N;                   // [N+1]
    int*   cursor  = row_ptr + N + 1;           // [N]
    int*   col     = cursor + N;                // [E]

    float* out_p    = (float*)d_out;            // [B]
    float* hidden_p = out_p + B;                // [B, 512]

    // ---- CSR build (once per call)
    hipMemsetAsync(cnt, 0, (size_t)N * sizeof(int), stream);
    k_count<<<(E + 255) / 256, 256, 0, stream>>>(dstv, cnt, E);
    k_dinv<<<(N + 255) / 256, 256, 0, stream>>>(cnt, dinv, N);
    k_scan<<<1, 256, 0, stream>>>(cnt, row_ptr, cursor, N);
    k_fill<<<(E + 255) / 256, 256, 0, stream>>>(srcv, dstv, dinv, cursor, col, coef, E);

    const float* hcur = x;
    int K = 64;
    for (int l = 0; l < 4; ++l) {
        k_gemm<<<(N + GROWS - 1) / GROWS, 256, 0, stream>>>(hcur, Wl[l], P0, N, K);
        hipMemsetAsync(sums, 0, 2 * D * sizeof(float), stream);
        k_gather<<<2048, 256, 0, stream>>>(row_ptr, col, coef, P0, dinv, bl[l],
                                           P1, sums, sumsq, N);
        k_finalize<<<1, 256, 0, stream>>>(sums, sumsq, gl[l], bel[l], 1.0f / (float)N);
        k_bn_tanh<<<((N * D / 4) + 255) / 256, 256, 0, stream>>>(P1, sums, sumsq, N * D / 4);
        hcur = P1;
        K = D;
    }

    k_pool<<<B, 256, 0, stream>>>(P1, batch, Wout, bout, out_p, hidden_p, N);
}

// Round 3
// 1442.101 us; speedup vs baseline: 2.4917x; 1.1204x over previous
//
#include <hip/hip_runtime.h>
#include <hip/hip_bf16.h>
#include <math.h>

#define D 256
#define EPS 1e-5f

// ---------------------------------------------------------------- CSR build
__global__ void k_count(const int* __restrict__ dst, int* __restrict__ cnt, int E) {
    int e = blockIdx.x * blockDim.x + threadIdx.x;
    if (e < E) atomicAdd(&cnt[dst[e]], 1);
}

__global__ void k_dinv(const int* __restrict__ cnt, float* __restrict__ dinv, int N) {
    int i = blockIdx.x * blockDim.x + threadIdx.x;
    if (i < N) dinv[i] = rsqrtf(1.0f + (float)cnt[i]);
}

// single-block two-pass prefix scan over N counts -> row_ptr[N+1], cursor[N]
__global__ void k_scan(const int* __restrict__ cnt, int* __restrict__ row_ptr,
                       int* __restrict__ cursor, int N) {
    __shared__ int part[257];
    int t = threadIdx.x;                  // 256 threads
    int chunk = (N + 255) / 256;
    int lo = t * chunk;
    int hi = lo + chunk; if (hi > N) hi = N; if (lo > N) lo = N;
    int s = 0;
    for (int i = lo; i < hi; ++i) s += cnt[i];
    part[t + 1] = s;
    if (t == 0) part[0] = 0;
    __syncthreads();
    if (t == 0) {
        for (int i = 1; i <= 256; ++i) part[i] += part[i - 1];
    }
    __syncthreads();
    int run = part[t];
    for (int i = lo; i < hi; ++i) {
        row_ptr[i] = run;
        cursor[i]  = run;
        run += cnt[i];
    }
    if (t == 255) row_ptr[N] = run;
}

__global__ void k_fill(const int* __restrict__ src, const int* __restrict__ dst,
                       const float* __restrict__ dinv, int* __restrict__ cursor,
                       int* __restrict__ col, float* __restrict__ coef, int E) {
    int e = blockIdx.x * blockDim.x + threadIdx.x;
    if (e >= E) return;
    int s = src[e], t = dst[e];
    int slot = atomicAdd(&cursor[t], 1);
    col[slot]  = s;
    coef[slot] = dinv[s] * dinv[t];
}

// ---------------------------------------------------------------- GEMM: out[N,256] = A[N,K] @ W[K,256]
#define GROWS 8
#define LDS_STRIDE 12
__global__ void k_gemm(const float* __restrict__ A, const float* __restrict__ W,
                       float* __restrict__ out, int N, int K) {
    __shared__ __align__(16) float lds[256 * LDS_STRIDE];
    int i0 = blockIdx.x * GROWS;
    int rows = N - i0; if (rows > GROWS) rows = GROWS;

    for (int idx = threadIdx.x; idx < rows * K; idx += 256) {
        int r = idx / K;
        int k = idx - r * K;
        lds[k * LDS_STRIDE + r] = A[(size_t)(i0 + r) * K + k];
    }
    if (rows < GROWS) {
        for (int idx = threadIdx.x; idx < GROWS * K; idx += 256) {
            int r = idx / K;
            int k = idx - r * K;
            if (r >= rows) lds[k * LDS_STRIDE + r] = 0.0f;
        }
    }
    __syncthreads();

    int d = threadIdx.x;
    float acc[GROWS];
#pragma unroll
    for (int r = 0; r < GROWS; ++r) acc[r] = 0.0f;

    for (int k = 0; k < K; ++k) {
        float w = W[(size_t)k * D + d];
        const float4* a4 = (const float4*)&lds[k * LDS_STRIDE];
        float4 a0 = a4[0];
        float4 a1 = a4[1];
        acc[0] = fmaf(a0.x, w, acc[0]);
        acc[1] = fmaf(a0.y, w, acc[1]);
        acc[2] = fmaf(a0.z, w, acc[2]);
        acc[3] = fmaf(a0.w, w, acc[3]);
        acc[4] = fmaf(a1.x, w, acc[4]);
        acc[5] = fmaf(a1.y, w, acc[5]);
        acc[6] = fmaf(a1.z, w, acc[6]);
        acc[7] = fmaf(a1.w, w, acc[7]);
    }
    for (int r = 0; r < rows; ++r) out[(size_t)(i0 + r) * D + d] = acc[r];
}

// ---------------------------------------------------------------- fused gather-aggregate + self-loop + bias + BN stats
// wave-per-node, float4-per-lane (64 lanes x 16B = full 1KB row per wave read),
// edge loop unrolled x4 -> 4 independent row-gathers in flight per wave.
__global__ void k_gather(const int* __restrict__ row_ptr, const int* __restrict__ col,
                         const float* __restrict__ coef, const float* __restrict__ hw,
                         const float* __restrict__ dinv, const float* __restrict__ b,
                         float* __restrict__ out, float* __restrict__ sums,
                         float* __restrict__ sumsq, int N) {
    const int lane = threadIdx.x & 63;
    const int wave = threadIdx.x >> 6;
    const float4* __restrict__ hw4 = (const float4*)hw;
    float4* __restrict__ out4 = (float4*)out;
    const float4 bv = ((const float4*)b)[lane];

    float4 s4  = make_float4(0.f, 0.f, 0.f, 0.f);
    float4 ss4 = make_float4(0.f, 0.f, 0.f, 0.f);

    int wslot  = blockIdx.x * 4 + wave;
    int wtotal = gridDim.x * 4;
    for (int i = wslot; i < N; i += wtotal) {
        int lo = row_ptr[i];
        int hi = row_ptr[i + 1];
        float di = dinv[i];
        float dd = di * di;
        float4 hv = hw4[(size_t)i * 64 + lane];
        float4 acc;
        acc.x = fmaf(hv.x, dd, bv.x);
        acc.y = fmaf(hv.y, dd, bv.y);
        acc.z = fmaf(hv.z, dd, bv.z);
        acc.w = fmaf(hv.w, dd, bv.w);

        int e = lo;
        for (; e + 4 <= hi; e += 4) {
            int   n0 = col[e],      n1 = col[e + 1],  n2 = col[e + 2],  n3 = col[e + 3];
            float c0 = coef[e],     c1 = coef[e + 1], c2 = coef[e + 2], c3 = coef[e + 3];
            float4 r0 = hw4[(size_t)n0 * 64 + lane];
            float4 r1 = hw4[(size_t)n1 * 64 + lane];
            float4 r2 = hw4[(size_t)n2 * 64 + lane];
            float4 r3 = hw4[(size_t)n3 * 64 + lane];
            acc.x = fmaf(r0.x, c0, acc.x); acc.y = fmaf(r0.y, c0, acc.y);
            acc.z = fmaf(r0.z, c0, acc.z); acc.w = fmaf(r0.w, c0, acc.w);
            acc.x = fmaf(r1.x, c1, acc.x); acc.y = fmaf(r1.y, c1, acc.y);
            acc.z = fmaf(r1.z, c1, acc.z); acc.w = fmaf(r1.w, c1, acc.w);
            acc.x = fmaf(r2.x, c2, acc.x); acc.y = fmaf(r2.y, c2, acc.y);
            acc.z = fmaf(r2.z, c2, acc.z); acc.w = fmaf(r2.w, c2, acc.w);
            acc.x = fmaf(r3.x, c3, acc.x); acc.y = fmaf(r3.y, c3, acc.y);
            acc.z = fmaf(r3.z, c3, acc.z); acc.w = fmaf(r3.w, c3, acc.w);
        }
        for (; e < hi; ++e) {
            int   sn = col[e];
            float c  = coef[e];
            float4 r = hw4[(size_t)sn * 64 + lane];
            acc.x = fmaf(r.x, c, acc.x); acc.y = fmaf(r.y, c, acc.y);
            acc.z = fmaf(r.z, c, acc.z); acc.w = fmaf(r.w, c, acc.w);
        }

        out4[(size_t)i * 64 + lane] = acc;
        s4.x += acc.x; s4.y += acc.y; s4.z += acc.z; s4.w += acc.w;
        ss4.x += acc.x * acc.x; ss4.y += acc.y * acc.y;
        ss4.z += acc.z * acc.z; ss4.w += acc.w * acc.w;
    }

    // block-level reduce of BN stats: feature f = lane*4+j, per-wave slice in LDS
    __shared__ float rs[4][256];
    __shared__ float rss[4][256];
    int f = lane * 4;
    rs[wave][f + 0] = s4.x;  rs[wave][f + 1] = s4.y;
    rs[wave][f + 2] = s4.z;  rs[wave][f + 3] = s4.w;
    rss[wave][f + 0] = ss4.x; rss[wave][f + 1] = ss4.y;
    rss[wave][f + 2] = ss4.z; rss[wave][f + 3] = ss4.w;
    __syncthreads();
    int t = threadIdx.x;
    float rsum  = rs[0][t] + rs[1][t] + rs[2][t] + rs[3][t];
    float rsum2 = rss[0][t] + rss[1][t] + rss[2][t] + rss[3][t];
    atomicAdd(&sums[t], rsum);
    atomicAdd(&sumsq[t], rsum2);
}

// sums -> scale, sumsq -> shift
__global__ void k_finalize(float* __restrict__ sums, float* __restrict__ sumsq,
                           const float* __restrict__ g, const float* __restrict__ be,
                           float Ninv) {
    int d = threadIdx.x;
    float mu = sums[d] * Ninv;
    float var = sumsq[d] * Ninv - mu * mu;
    float sc = g[d] * rsqrtf(var + EPS);
    sums[d] = sc;
    sumsq[d] = be[d] - mu * sc;
}

// h <- tanh(h*scale + shift), float4-vectorized
__global__ void k_bn_tanh(float* __restrict__ h, const float* __restrict__ scale,
                          const float* __restrict__ shift, int n4) {
    int i = blockIdx.x * blockDim.x + threadIdx.x;
    if (i >= n4) return;
    float4 v = ((float4*)h)[i];
    int d = (i & 63) * 4;
    v.x = tanhf(fmaf(v.x, scale[d + 0], shift[d + 0]));
    v.y = tanhf(fmaf(v.y, scale[d + 1], shift[d + 1]));
    v.z = tanhf(fmaf(v.z, scale[d + 2], shift[d + 2]));
    v.w = tanhf(fmaf(v.w, scale[d + 3], shift[d + 3]));
    ((float4*)h)[i] = v;
}

// ---------------------------------------------------------------- pooling + output GEMV
__device__ __forceinline__ int lb(const int* __restrict__ a, int n, int v) {
    int lo = 0, hi = n;
    while (lo < hi) {
        int mid = (lo + hi) >> 1;
        if (a[mid] < v) lo = mid + 1; else hi = mid;
    }
    return lo;
}

__global__ void k_pool(const float* __restrict__ h, const int* __restrict__ batch,
                       const float* __restrict__ Wout, const float* __restrict__ bout,
                       float* __restrict__ out, float* __restrict__ hidden, int N) {
    int g = blockIdx.x;
    int d = threadIdx.x;
    int lo = lb(batch, N, g);
    int hi = lb(batch, N, g + 1);
    float mx = -INFINITY, sm = 0.0f;
    for (int i = lo; i < hi; ++i) {
        float v = h[(size_t)i * D + d];
        mx = fmaxf(mx, v);
        sm += v;
    }
    float mean = sm / (float)(hi - lo);
    hidden[(size_t)g * (2 * D) + d] = mx;
    hidden[(size_t)g * (2 * D) + D + d] = mean;

    float p = mx * Wout[d] + mean * Wout[D + d];
    __shared__ float red[256];
    red[d] = p;
    __syncthreads();
    for (int s = 128; s > 0; s >>= 1) {
        if (d < s) red[d] += red[d + s];
        __syncthreads();
    }
    if (d == 0) out[g] = red[0] + bout[0];
}

// ----------------------------------------------------------------
extern "C" void kernel_launch(void* const* d_in, const int* in_sizes, int n_in,
                              void* d_out, int out_size, void* d_ws, size_t ws_size,
                              hipStream_t stream) {
    const float* x          = (const float*)d_in[0];
    const int*   edge_index = (const int*)d_in[1];
    const int*   batch      = (const int*)d_in[2];
    const float* Wl[4] = {(const float*)d_in[4], (const float*)d_in[6],
                          (const float*)d_in[8], (const float*)d_in[10]};
    const float* bl[4] = {(const float*)d_in[5], (const float*)d_in[7],
                          (const float*)d_in[9], (const float*)d_in[11]};
    const float* gl[4]  = {(const float*)d_in[12], (const float*)d_in[14],
                           (const float*)d_in[16], (const float*)d_in[18]};
    const float* bel[4] = {(const float*)d_in[13], (const float*)d_in[15],
                           (const float*)d_in[17], (const float*)d_in[19]};
    const float* Wout = (const float*)d_in[20];
    const float* bout = (const float*)d_in[21];

    const int N = in_sizes[0] / 64;       // 50000
    const int E = in_sizes[1] / 2;        // 800000
    const int B = out_size / (1 + 2 * D); // 1000

    const int* srcv = edge_index;
    const int* dstv = edge_index + E;

    // workspace carve-up
    float* P0      = (float*)d_ws;              // [N,D] hw = h_in @ W
    float* P1      = P0 + (size_t)N * D;        // [N,D] layer output (ping)
    float* dinv    = P1 + (size_t)N * D;        // [N]
    float* sums    = dinv + N;                  // [D] -> scale
    float* sumsq   = sums + D;                  // [D] -> shift
    float* coef    = sumsq + D;                 // [E]
    int*   cnt     = (int*)(coef + E);          // [N]
    int*   row_ptr = cnt + N;                   // [N+1]
    int*   cursor  = row_ptr + N + 1;           // [N]
    int*   col     = cursor + N;                // [E]

    float* out_p    = (float*)d_out;            // [B]
    float* hidden_p = out_p + B;                // [B, 512]

    // ---- CSR build (once per call)
    hipMemsetAsync(cnt, 0, (size_t)N * sizeof(int), stream);
    k_count<<<(E + 255) / 256, 256, 0, stream>>>(dstv, cnt, E);
    k_dinv<<<(N + 255) / 256, 256, 0, stream>>>(cnt, dinv, N);
    k_scan<<<1, 256, 0, stream>>>(cnt, row_ptr, cursor, N);
    k_fill<<<(E + 255) / 256, 256, 0, stream>>>(srcv, dstv, dinv, cursor, col, coef, E);

    const float* hcur = x;
    int K = 64;
    for (int l = 0; l < 4; ++l) {
        k_gemm<<<(N + GROWS - 1) / GROWS, 256, 0, stream>>>(hcur, Wl[l], P0, N, K);
        hipMemsetAsync(sums, 0, 2 * D * sizeof(float), stream);
        k_gather<<<2048, 256, 0, stream>>>(row_ptr, col, coef, P0, dinv, bl[l],
                                           P1, sums, sumsq, N);
        k_finalize<<<1, 256, 0, stream>>>(sums, sumsq, gl[l], bel[l], 1.0f / (float)N);
        k_bn_tanh<<<((N * D / 4) + 255) / 256, 256, 0, stream>>>(P1, sums, sumsq, N * D / 4);
        hcur = P1;
        K = D;
    }

    k_pool<<<B, 256, 0, stream>>>(P1, batch, Wout, bout, out_p, hidden_p, N);
}

// Round 4
// 969.910 us; speedup vs baseline: 3.7047x; 1.4868x over previous
//
#include <hip/hip_runtime.h>
#include <hip/hip_bf16.h>
#include <math.h>

#define D 256
#define EPS 1e-5f

typedef _Float16 f16;
typedef _Float16 f16x4 __attribute__((ext_vector_type(4)));
typedef _Float16 f16x8 __attribute__((ext_vector_type(8)));
typedef float f32x4v __attribute__((ext_vector_type(4)));

// ---------------------------------------------------------------- CSR build
__global__ void k_count(const int* __restrict__ dst, int* __restrict__ cnt, int E) {
    int e = blockIdx.x * blockDim.x + threadIdx.x;
    if (e < E) atomicAdd(&cnt[dst[e]], 1);
}

__global__ void k_dinv(const int* __restrict__ cnt, float* __restrict__ dinv, int N) {
    int i = blockIdx.x * blockDim.x + threadIdx.x;
    if (i < N) dinv[i] = rsqrtf(1.0f + (float)cnt[i]);
}

// single-block two-pass prefix scan over N counts -> row_ptr[N+1], cursor[N]
__global__ void k_scan(const int* __restrict__ cnt, int* __restrict__ row_ptr,
                       int* __restrict__ cursor, int N) {
    __shared__ int part[257];
    int t = threadIdx.x;
    int chunk = (N + 255) / 256;
    int lo = t * chunk;
    int hi = lo + chunk; if (hi > N) hi = N; if (lo > N) lo = N;
    int s = 0;
    for (int i = lo; i < hi; ++i) s += cnt[i];
    part[t + 1] = s;
    if (t == 0) part[0] = 0;
    __syncthreads();
    if (t == 0) {
        for (int i = 1; i <= 256; ++i) part[i] += part[i - 1];
    }
    __syncthreads();
    int run = part[t];
    for (int i = lo; i < hi; ++i) {
        row_ptr[i] = run;
        cursor[i]  = run;
        run += cnt[i];
    }
    if (t == 255) row_ptr[N] = run;
}

__global__ void k_fill(const int* __restrict__ src, const int* __restrict__ dst,
                       const float* __restrict__ dinv, int* __restrict__ cursor,
                       int* __restrict__ col, float* __restrict__ coef, int E) {
    int e = blockIdx.x * blockDim.x + threadIdx.x;
    if (e >= E) return;
    int s = src[e], t = dst[e];
    int slot = atomicAdd(&cursor[t], 1);
    col[slot]  = s;
    coef[slot] = dinv[s] * dinv[t];
}

// ---------------------------------------------------------------- casts / weight prep
__global__ void k_cast(const float* __restrict__ in, f16* __restrict__ o, int n4) {
    int i = blockIdx.x * 256 + threadIdx.x;
    if (i >= n4) return;
    float4 v = ((const float4*)in)[i];
    f16x4 h = {(f16)v.x, (f16)v.y, (f16)v.z, (f16)v.w};
    ((f16x4*)o)[i] = h;
}

// Wt[d][k] = (f16) W[k][d];  W is [K][256]
__global__ void k_prep_w(const float* __restrict__ W, f16* __restrict__ Wt, int K) {
    int idx = blockIdx.x * 256 + threadIdx.x;   // = k*256 + d
    if (idx >= K * 256) return;
    int k = idx >> 8, d = idx & 255;
    Wt[(size_t)d * K + k] = (f16)W[idx];
}

// ---------------------------------------------------------------- MFMA GEMM
// outh[N,256] = A[N,K] @ W[K,256], all f16 in / f16 out, fp32 accumulate.
// block = 256 thr = 4 waves; block tile 64 rows x 64 cols (grid.y=4 col blocks).
// wave w: rows w*16..+15; 4 col sub-tiles of 16 via mfma_f32_16x16x32_f16.
#define KSTEP 32
#define ATS 40   // LDS row stride in halfs: 80B -> 16B-aligned, 2-way conflict (free)
__global__ __launch_bounds__(256)
void k_gemm(const f16* __restrict__ A, const f16* __restrict__ Wt,
            f16* __restrict__ outh, int N, int K) {
    __shared__ __align__(16) f16 As[64 * ATS];
    __shared__ __align__(16) f16 Bs[64 * ATS];
    const int r0 = blockIdx.x * 64;
    const int c0 = blockIdx.y * 64;
    const int t = threadIdx.x;
    const int lane = t & 63, wave = t >> 6;
    const int quad = lane >> 4, m = lane & 15;

    f32x4v acc[4] = {{0.f,0.f,0.f,0.f},{0.f,0.f,0.f,0.f},
                     {0.f,0.f,0.f,0.f},{0.f,0.f,0.f,0.f}};
    const int sr = t >> 2;        // staging row 0..63
    const int sc = (t & 3) * 8;   // k-chunk offset (halfs)

    for (int k0 = 0; k0 < K; k0 += KSTEP) {
        uint4 av = make_uint4(0u, 0u, 0u, 0u);
        int gr = r0 + sr;
        if (gr < N) av = *(const uint4*)(A + (size_t)gr * K + k0 + sc);
        *(uint4*)(As + sr * ATS + sc) = av;
        uint4 bv = *(const uint4*)(Wt + (size_t)(c0 + sr) * K + k0 + sc);
        *(uint4*)(Bs + sr * ATS + sc) = bv;
        __syncthreads();

        f16x8 af = *(const f16x8*)(As + (wave * 16 + m) * ATS + quad * 8);
#pragma unroll
        for (int c = 0; c < 4; ++c) {
            f16x8 bf = *(const f16x8*)(Bs + (c * 16 + m) * ATS + quad * 8);
            acc[c] = __builtin_amdgcn_mfma_f32_16x16x32_f16(af, bf, acc[c], 0, 0, 0);
        }
        __syncthreads();
    }

#pragma unroll
    for (int c = 0; c < 4; ++c) {
#pragma unroll
        for (int r = 0; r < 4; ++r) {
            int row = r0 + wave * 16 + quad * 4 + r;
            if (row < N) outh[(size_t)row * D + c0 + c * 16 + m] = (f16)acc[c][r];
        }
    }
}

// ---------------------------------------------------------------- fused gather + self-loop + bias + BN stats
// wave-per-node; lane holds features lane*4..+3 (f16x4, 8B -> 512B row per wave);
// edge loop unrolled x4 for MLP. Accumulate fp32, write agg fp32.
__global__ void k_gather(const int* __restrict__ row_ptr, const int* __restrict__ col,
                         const float* __restrict__ coef, const f16* __restrict__ hw,
                         const float* __restrict__ dinv, const float* __restrict__ b,
                         float* __restrict__ out, float* __restrict__ sums,
                         float* __restrict__ sumsq, int N) {
    const int lane = threadIdx.x & 63;
    const int wave = threadIdx.x >> 6;
    const f16x4* __restrict__ hw4 = (const f16x4*)hw;
    float4* __restrict__ out4 = (float4*)out;
    const float4 bv = ((const float4*)b)[lane];

    float4 s4  = make_float4(0.f, 0.f, 0.f, 0.f);
    float4 ss4 = make_float4(0.f, 0.f, 0.f, 0.f);

    int wslot  = blockIdx.x * 4 + wave;
    int wtotal = gridDim.x * 4;
    for (int i = wslot; i < N; i += wtotal) {
        int lo = row_ptr[i];
        int hi = row_ptr[i + 1];
        float di = dinv[i];
        float dd = di * di;
        f16x4 hv = hw4[(size_t)i * 64 + lane];
        float4 acc;
        acc.x = fmaf((float)hv[0], dd, bv.x);
        acc.y = fmaf((float)hv[1], dd, bv.y);
        acc.z = fmaf((float)hv[2], dd, bv.z);
        acc.w = fmaf((float)hv[3], dd, bv.w);

        int e = lo;
        for (; e + 4 <= hi; e += 4) {
            int   n0 = col[e],      n1 = col[e + 1],  n2 = col[e + 2],  n3 = col[e + 3];
            float c0 = coef[e],     c1 = coef[e + 1], c2 = coef[e + 2], c3 = coef[e + 3];
            f16x4 r0 = hw4[(size_t)n0 * 64 + lane];
            f16x4 r1 = hw4[(size_t)n1 * 64 + lane];
            f16x4 r2 = hw4[(size_t)n2 * 64 + lane];
            f16x4 r3 = hw4[(size_t)n3 * 64 + lane];
            acc.x = fmaf((float)r0[0], c0, acc.x); acc.y = fmaf((float)r0[1], c0, acc.y);
            acc.z = fmaf((float)r0[2], c0, acc.z); acc.w = fmaf((float)r0[3], c0, acc.w);
            acc.x = fmaf((float)r1[0], c1, acc.x); acc.y = fmaf((float)r1[1], c1, acc.y);
            acc.z = fmaf((float)r1[2], c1, acc.z); acc.w = fmaf((float)r1[3], c1, acc.w);
            acc.x = fmaf((float)r2[0], c2, acc.x); acc.y = fmaf((float)r2[1], c2, acc.y);
            acc.z = fmaf((float)r2[2], c2, acc.z); acc.w = fmaf((float)r2[3], c2, acc.w);
            acc.x = fmaf((float)r3[0], c3, acc.x); acc.y = fmaf((float)r3[1], c3, acc.y);
            acc.z = fmaf((float)r3[2], c3, acc.z); acc.w = fmaf((float)r3[3], c3, acc.w);
        }
        for (; e < hi; ++e) {
            int   sn = col[e];
            float c  = coef[e];
            f16x4 r = hw4[(size_t)sn * 64 + lane];
            acc.x = fmaf((float)r[0], c, acc.x); acc.y = fmaf((float)r[1], c, acc.y);
            acc.z = fmaf((float)r[2], c, acc.z); acc.w = fmaf((float)r[3], c, acc.w);
        }

        out4[(size_t)i * 64 + lane] = acc;
        s4.x += acc.x; s4.y += acc.y; s4.z += acc.z; s4.w += acc.w;
        ss4.x += acc.x * acc.x; ss4.y += acc.y * acc.y;
        ss4.z += acc.z * acc.z; ss4.w += acc.w * acc.w;
    }

    __shared__ float rs[4][256];
    __shared__ float rss[4][256];
    int f = lane * 4;
    rs[wave][f + 0] = s4.x;  rs[wave][f + 1] = s4.y;
    rs[wave][f + 2] = s4.z;  rs[wave][f + 3] = s4.w;
    rss[wave][f + 0] = ss4.x; rss[wave][f + 1] = ss4.y;
    rss[wave][f + 2] = ss4.z; rss[wave][f + 3] = ss4.w;
    __syncthreads();
    int t = threadIdx.x;
    float rsum  = rs[0][t] + rs[1][t] + rs[2][t] + rs[3][t];
    float rsum2 = rss[0][t] + rss[1][t] + rss[2][t] + rss[3][t];
    atomicAdd(&sums[t], rsum);
    atomicAdd(&sumsq[t], rsum2);
}

// sums -> scale, sumsq -> shift
__global__ void k_finalize(float* __restrict__ sums, float* __restrict__ sumsq,
                           const float* __restrict__ g, const float* __restrict__ be,
                           float Ninv) {
    int d = threadIdx.x;
    float mu = sums[d] * Ninv;
    float var = sumsq[d] * Ninv - mu * mu;
    float sc = g[d] * rsqrtf(var + EPS);
    sums[d] = sc;
    sumsq[d] = be[d] - mu * sc;
}

// h <- tanh(h*scale + shift); writes f16 activations (next GEMM input);
// on the last layer writes fp32 in place (pool input) instead.
__global__ void k_bn_tanh(float* __restrict__ h, const float* __restrict__ scale,
                          const float* __restrict__ shift, f16* __restrict__ hh,
                          int n4, int last) {
    int i = blockIdx.x * blockDim.x + threadIdx.x;
    if (i >= n4) return;
    float4 v = ((float4*)h)[i];
    int d = (i & 63) * 4;
    v.x = tanhf(fmaf(v.x, scale[d + 0], shift[d + 0]));
    v.y = tanhf(fmaf(v.y, scale[d + 1], shift[d + 1]));
    v.z = tanhf(fmaf(v.z, scale[d + 2], shift[d + 2]));
    v.w = tanhf(fmaf(v.w, scale[d + 3], shift[d + 3]));
    if (last) {
        ((float4*)h)[i] = v;
    } else {
        f16x4 o = {(f16)v.x, (f16)v.y, (f16)v.z, (f16)v.w};
        ((f16x4*)hh)[i] = o;
    }
}

// ---------------------------------------------------------------- pooling + output GEMV
__device__ __forceinline__ int lb(const int* __restrict__ a, int n, int v) {
    int lo = 0, hi = n;
    while (lo < hi) {
        int mid = (lo + hi) >> 1;
        if (a[mid] < v) lo = mid + 1; else hi = mid;
    }
    return lo;
}

__global__ void k_pool(const float* __restrict__ h, const int* __restrict__ batch,
                       const float* __restrict__ Wout, const float* __restrict__ bout,
                       float* __restrict__ out, float* __restrict__ hidden, int N) {
    int g = blockIdx.x;
    int d = threadIdx.x;
    int lo = lb(batch, N, g);
    int hi = lb(batch, N, g + 1);
    float mx = -INFINITY, sm = 0.0f;
    for (int i = lo; i < hi; ++i) {
        float v = h[(size_t)i * D + d];
        mx = fmaxf(mx, v);
        sm += v;
    }
    float mean = sm / (float)(hi - lo);
    hidden[(size_t)g * (2 * D) + d] = mx;
    hidden[(size_t)g * (2 * D) + D + d] = mean;

    float p = mx * Wout[d] + mean * Wout[D + d];
    __shared__ float red[256];
    red[d] = p;
    __syncthreads();
    for (int s = 128; s > 0; s >>= 1) {
        if (d < s) red[d] += red[d + s];
        __syncthreads();
    }
    if (d == 0) out[g] = red[0] + bout[0];
}

// ----------------------------------------------------------------
extern "C" void kernel_launch(void* const* d_in, const int* in_sizes, int n_in,
                              void* d_out, int out_size, void* d_ws, size_t ws_size,
                              hipStream_t stream) {
    const float* x          = (const float*)d_in[0];
    const int*   edge_index = (const int*)d_in[1];
    const int*   batch      = (const int*)d_in[2];
    const float* Wl[4] = {(const float*)d_in[4], (const float*)d_in[6],
                          (const float*)d_in[8], (const float*)d_in[10]};
    const float* bl[4] = {(const float*)d_in[5], (const float*)d_in[7],
                          (const float*)d_in[9], (const float*)d_in[11]};
    const float* gl[4]  = {(const float*)d_in[12], (const float*)d_in[14],
                           (const float*)d_in[16], (const float*)d_in[18]};
    const float* bel[4] = {(const float*)d_in[13], (const float*)d_in[15],
                           (const float*)d_in[17], (const float*)d_in[19]};
    const float* Wout = (const float*)d_in[20];
    const float* bout = (const float*)d_in[21];

    const int N = in_sizes[0] / 64;       // 50000
    const int E = in_sizes[1] / 2;        // 800000
    const int B = out_size / (1 + 2 * D); // 1000

    const int* srcv = edge_index;
    const int* dstv = edge_index + E;

    // workspace carve-up
    float* P1      = (float*)d_ws;              // [N,D] fp32 agg / final h
    f16*   hw_h    = (f16*)(P1 + (size_t)N * D);// [N,D] f16 GEMM out (gather input)
    f16*   hh      = hw_h + (size_t)N * D;      // [N,D] f16 activations (GEMM input)
    f16*   xh      = hh + (size_t)N * D;        // [N,64] f16 cast of x
    f16*   Wt      = xh + (size_t)N * 64;       // [256,256] f16 transposed weights
    float* dinv    = (float*)(Wt + 256 * 256);  // [N]
    float* sums    = dinv + N;                  // [D] -> scale
    float* sumsq   = sums + D;                  // [D] -> shift
    float* coef    = sumsq + D;                 // [E]
    int*   cnt     = (int*)(coef + E);          // [N]
    int*   row_ptr = cnt + N;                   // [N+1]
    int*   cursor  = row_ptr + N + 1;           // [N]
    int*   col     = cursor + N;                // [E]

    float* out_p    = (float*)d_out;            // [B]
    float* hidden_p = out_p + B;                // [B, 512]

    // ---- CSR build (once per call)
    hipMemsetAsync(cnt, 0, (size_t)N * sizeof(int), stream);
    k_count<<<(E + 255) / 256, 256, 0, stream>>>(dstv, cnt, E);
    k_dinv<<<(N + 255) / 256, 256, 0, stream>>>(cnt, dinv, N);
    k_scan<<<1, 256, 0, stream>>>(cnt, row_ptr, cursor, N);
    k_fill<<<(E + 255) / 256, 256, 0, stream>>>(srcv, dstv, dinv, cursor, col, coef, E);

    // x -> f16
    k_cast<<<(N * 64 / 4 + 255) / 256, 256, 0, stream>>>(x, xh, N * 64 / 4);

    const f16* hcur = xh;
    int K = 64;
    for (int l = 0; l < 4; ++l) {
        k_prep_w<<<K, 256, 0, stream>>>(Wl[l], Wt, K);
        dim3 gg((N + 63) / 64, 4);
        k_gemm<<<gg, 256, 0, stream>>>(hcur, Wt, hw_h, N, K);
        hipMemsetAsync(sums, 0, 2 * D * sizeof(float), stream);
        k_gather<<<2048, 256, 0, stream>>>(row_ptr, col, coef, hw_h, dinv, bl[l],
                                           P1, sums, sumsq, N);
        k_finalize<<<1, 256, 0, stream>>>(sums, sumsq, gl[l], bel[l], 1.0f / (float)N);
        k_bn_tanh<<<((N * D / 4) + 255) / 256, 256, 0, stream>>>(
            P1, sums, sumsq, hh, N * D / 4, l == 3);
        hcur = hh;
        K = D;
    }

    k_pool<<<B, 256, 0, stream>>>(P1, batch, Wout, bout, out_p, hidden_p, N);
}

// Round 6
// 794.965 us; speedup vs baseline: 4.5200x; 1.2201x over previous
//
#include <hip/hip_runtime.h>
#include <hip/hip_bf16.h>
#include <math.h>

#define D 256
#define EPS 1e-5f
#define SCAN_NB 256

typedef _Float16 f16;
typedef _Float16 f16x4 __attribute__((ext_vector_type(4)));
typedef _Float16 f16x8 __attribute__((ext_vector_type(8)));
typedef float f32x4v __attribute__((ext_vector_type(4)));

// ---------------------------------------------------------------- CSR build
__global__ void k_count(const int* __restrict__ dst, int* __restrict__ cnt, int E) {
    int e = blockIdx.x * blockDim.x + threadIdx.x;
    if (e < E) atomicAdd(&cnt[dst[e]], 1);
}

__global__ void k_dinv(const int* __restrict__ cnt, float* __restrict__ dinv, int N) {
    int i = blockIdx.x * blockDim.x + threadIdx.x;
    if (i < N) dinv[i] = rsqrtf(1.0f + (float)cnt[i]);
}

// ---- 3-phase hierarchical exclusive scan
// A: each of SCAN_NB blocks scans its contiguous chunk (coalesced, LDS Hillis-Steele)
__global__ void k_scan_part(const int* __restrict__ cnt, int* __restrict__ row_ptr,
                            int* __restrict__ partial, int N, int C) {
    __shared__ int sdata[256];
    int b = blockIdx.x, t = threadIdx.x;
    int base = b * C;
    int end = base + C; if (end > N) end = N;
    int running = 0;
    for (int ts = base; ts < end; ts += 256) {
        int idx = ts + t;
        int val = (idx < end) ? cnt[idx] : 0;
        sdata[t] = val;
        __syncthreads();
        for (int s = 1; s < 256; s <<= 1) {
            int v = (t >= s) ? sdata[t - s] : 0;
            __syncthreads();
            sdata[t] += v;
            __syncthreads();
        }
        if (idx < end) row_ptr[idx] = running + sdata[t] - val;  // local exclusive; OWN chunk only
        running += sdata[255];
        __syncthreads();
    }
    if (t == 0) partial[b] = running;
}

// B: exclusive scan of the 256 block partials (1 block)
__global__ void k_scan_off(int* __restrict__ partial) {
    __shared__ int sdata[256];
    int t = threadIdx.x;
    int val = partial[t];
    sdata[t] = val;
    __syncthreads();
    for (int s = 1; s < 256; s <<= 1) {
        int v = (t >= s) ? sdata[t - s] : 0;
        __syncthreads();
        sdata[t] += v;
        __syncthreads();
    }
    partial[t] = sdata[t] - val;
}

// C: add block offsets, emit cursor, close row_ptr
__global__ void k_scan_add(int* __restrict__ row_ptr, int* __restrict__ cursor,
                           const int* __restrict__ partial, int N, int C, int E) {
    int i = blockIdx.x * 256 + threadIdx.x;
    if (i < N) {
        int v = row_ptr[i] + partial[i / C];
        row_ptr[i] = v;
        cursor[i]  = v;
    }
    if (i == N) row_ptr[N] = E;
}

__global__ void k_fill(const int* __restrict__ src, const int* __restrict__ dst,
                       const float* __restrict__ dinv, int* __restrict__ cursor,
                       int* __restrict__ col, float* __restrict__ coef, int E) {
    int e = blockIdx.x * blockDim.x + threadIdx.x;
    if (e >= E) return;
    int s = src[e], t = dst[e];
    int slot = atomicAdd(&cursor[t], 1);
    col[slot]  = s;
    coef[slot] = dinv[s] * dinv[t];
}

// ---------------------------------------------------------------- casts / weight prep
__global__ void k_cast(const float* __restrict__ in, f16* __restrict__ o, int n4) {
    int i = blockIdx.x * 256 + threadIdx.x;
    if (i >= n4) return;
    float4 v = ((const float4*)in)[i];
    f16x4 h = {(f16)v.x, (f16)v.y, (f16)v.z, (f16)v.w};
    ((f16x4*)o)[i] = h;
}

// Wt[d][k] = (f16) W[k][d];  W is [K][256]
__global__ void k_prep_w(const float* __restrict__ W, f16* __restrict__ Wt, int K) {
    int idx = blockIdx.x * 256 + threadIdx.x;   // = k*256 + d
    if (idx >= K * 256) return;
    int k = idx >> 8, d = idx & 255;
    Wt[(size_t)d * K + k] = (f16)W[idx];
}

// ---------------------------------------------------------------- MFMA GEMM
#define KSTEP 32
#define ATS 40
__global__ __launch_bounds__(256)
void k_gemm(const f16* __restrict__ A, const f16* __restrict__ Wt,
            f16* __restrict__ outh, int N, int K) {
    __shared__ __align__(16) f16 As[64 * ATS];
    __shared__ __align__(16) f16 Bs[64 * ATS];
    const int r0 = blockIdx.x * 64;
    const int c0 = blockIdx.y * 64;
    const int t = threadIdx.x;
    const int lane = t & 63, wave = t >> 6;
    const int quad = lane >> 4, m = lane & 15;

    f32x4v acc[4] = {{0.f,0.f,0.f,0.f},{0.f,0.f,0.f,0.f},
                     {0.f,0.f,0.f,0.f},{0.f,0.f,0.f,0.f}};
    const int sr = t >> 2;
    const int sc = (t & 3) * 8;

    for (int k0 = 0; k0 < K; k0 += KSTEP) {
        uint4 av = make_uint4(0u, 0u, 0u, 0u);
        int gr = r0 + sr;
        if (gr < N) av = *(const uint4*)(A + (size_t)gr * K + k0 + sc);
        *(uint4*)(As + sr * ATS + sc) = av;
        uint4 bv = *(const uint4*)(Wt + (size_t)(c0 + sr) * K + k0 + sc);
        *(uint4*)(Bs + sr * ATS + sc) = bv;
        __syncthreads();

        f16x8 af = *(const f16x8*)(As + (wave * 16 + m) * ATS + quad * 8);
#pragma unroll
        for (int c = 0; c < 4; ++c) {
            f16x8 bf = *(const f16x8*)(Bs + (c * 16 + m) * ATS + quad * 8);
            acc[c] = __builtin_amdgcn_mfma_f32_16x16x32_f16(af, bf, acc[c], 0, 0, 0);
        }
        __syncthreads();
    }

#pragma unroll
    for (int c = 0; c < 4; ++c) {
#pragma unroll
        for (int r = 0; r < 4; ++r) {
            int row = r0 + wave * 16 + quad * 4 + r;
            if (row < N) outh[(size_t)row * D + c0 + c * 16 + m] = (f16)acc[c][r];
        }
    }
}

// ---------------------------------------------------------------- fused gather + self-loop + bias + BN stats
__global__ void k_gather(const int* __restrict__ row_ptr, const int* __restrict__ col,
                         const float* __restrict__ coef, const f16* __restrict__ hw,
                         const float* __restrict__ dinv, const float* __restrict__ b,
                         float* __restrict__ out, float* __restrict__ sums,
                         float* __restrict__ sumsq, int N) {
    const int lane = threadIdx.x & 63;
    const int wave = threadIdx.x >> 6;
    const f16x4* __restrict__ hw4 = (const f16x4*)hw;
    float4* __restrict__ out4 = (float4*)out;
    const float4 bv = ((const float4*)b)[lane];

    float4 s4  = make_float4(0.f, 0.f, 0.f, 0.f);
    float4 ss4 = make_float4(0.f, 0.f, 0.f, 0.f);

    int wslot  = blockIdx.x * 4 + wave;
    int wtotal = gridDim.x * 4;
    for (int i = wslot; i < N; i += wtotal) {
        int lo = row_ptr[i];
        int hi = row_ptr[i + 1];
        float di = dinv[i];
        float dd = di * di;
        f16x4 hv = hw4[(size_t)i * 64 + lane];
        float4 acc;
        acc.x = fmaf((float)hv[0], dd, bv.x);
        acc.y = fmaf((float)hv[1], dd, bv.y);
        acc.z = fmaf((float)hv[2], dd, bv.z);
        acc.w = fmaf((float)hv[3], dd, bv.w);

        int e = lo;
        for (; e + 4 <= hi; e += 4) {
            int   n0 = col[e],      n1 = col[e + 1],  n2 = col[e + 2],  n3 = col[e + 3];
            float c0 = coef[e],     c1 = coef[e + 1], c2 = coef[e + 2], c3 = coef[e + 3];
            f16x4 r0 = hw4[(size_t)n0 * 64 + lane];
            f16x4 r1 = hw4[(size_t)n1 * 64 + lane];
            f16x4 r2 = hw4[(size_t)n2 * 64 + lane];
            f16x4 r3 = hw4[(size_t)n3 * 64 + lane];
            acc.x = fmaf((float)r0[0], c0, acc.x); acc.y = fmaf((float)r0[1], c0, acc.y);
            acc.z = fmaf((float)r0[2], c0, acc.z); acc.w = fmaf((float)r0[3], c0, acc.w);
            acc.x = fmaf((float)r1[0], c1, acc.x); acc.y = fmaf((float)r1[1], c1, acc.y);
            acc.z = fmaf((float)r1[2], c1, acc.z); acc.w = fmaf((float)r1[3], c1, acc.w);
            acc.x = fmaf((float)r2[0], c2, acc.x); acc.y = fmaf((float)r2[1], c2, acc.y);
            acc.z = fmaf((float)r2[2], c2, acc.z); acc.w = fmaf((float)r2[3], c2, acc.w);
            acc.x = fmaf((float)r3[0], c3, acc.x); acc.y = fmaf((float)r3[1], c3, acc.y);
            acc.z = fmaf((float)r3[2], c3, acc.z); acc.w = fmaf((float)r3[3], c3, acc.w);
        }
        for (; e < hi; ++e) {
            int   sn = col[e];
            float c  = coef[e];
            f16x4 r = hw4[(size_t)sn * 64 + lane];
            acc.x = fmaf((float)r[0], c, acc.x); acc.y = fmaf((float)r[1], c, acc.y);
            acc.z = fmaf((float)r[2], c, acc.z); acc.w = fmaf((float)r[3], c, acc.w);
        }

        out4[(size_t)i * 64 + lane] = acc;
        s4.x += acc.x; s4.y += acc.y; s4.z += acc.z; s4.w += acc.w;
        ss4.x += acc.x * acc.x; ss4.y += acc.y * acc.y;
        ss4.z += acc.z * acc.z; ss4.w += acc.w * acc.w;
    }

    __shared__ float rs[4][256];
    __shared__ float rss[4][256];
    int f = lane * 4;
    rs[wave][f + 0] = s4.x;  rs[wave][f + 1] = s4.y;
    rs[wave][f + 2] = s4.z;  rs[wave][f + 3] = s4.w;
    rss[wave][f + 0] = ss4.x; rss[wave][f + 1] = ss4.y;
    rss[wave][f + 2] = ss4.z; rss[wave][f + 3] = ss4.w;
    __syncthreads();
    int t = threadIdx.x;
    float rsum  = rs[0][t] + rs[1][t] + rs[2][t] + rs[3][t];
    float rsum2 = rss[0][t] + rss[1][t] + rss[2][t] + rss[3][t];
    atomicAdd(&sums[t], rsum);
    atomicAdd(&sumsq[t], rsum2);
}

// ---------------------------------------------------------------- BN + tanh (finalize folded in)
__global__ void k_bn_tanh(float* __restrict__ h, const float* __restrict__ sums,
                          const float* __restrict__ sumsq, const float* __restrict__ g,
                          const float* __restrict__ be, float Ninv,
                          f16* __restrict__ hh, int n4, int last) {
    int i = blockIdx.x * blockDim.x + threadIdx.x;
    if (i >= n4) return;
    int d = (i & 63) * 4;
    float4 v = ((float4*)h)[i];
    float sc[4], sh[4];
#pragma unroll
    for (int j = 0; j < 4; ++j) {
        float mu  = sums[d + j] * Ninv;
        float var = sumsq[d + j] * Ninv - mu * mu;
        float s   = g[d + j] * rsqrtf(var + EPS);
        sc[j] = s;
        sh[j] = be[d + j] - mu * s;
    }
    v.x = tanhf(fmaf(v.x, sc[0], sh[0]));
    v.y = tanhf(fmaf(v.y, sc[1], sh[1]));
    v.z = tanhf(fmaf(v.z, sc[2], sh[2]));
    v.w = tanhf(fmaf(v.w, sc[3], sh[3]));
    if (last) {
        ((float4*)h)[i] = v;
    } else {
        f16x4 o = {(f16)v.x, (f16)v.y, (f16)v.z, (f16)v.w};
        ((f16x4*)hh)[i] = o;
    }
}

// ---------------------------------------------------------------- pooling + output GEMV
__device__ __forceinline__ int lb(const int* __restrict__ a, int n, int v) {
    int lo = 0, hi = n;
    while (lo < hi) {
        int mid = (lo + hi) >> 1;
        if (a[mid] < v) lo = mid + 1; else hi = mid;
    }
    return lo;
}

__global__ void k_pool(const float* __restrict__ h, const int* __restrict__ batch,
                       const float* __restrict__ Wout, const float* __restrict__ bout,
                       float* __restrict__ out, float* __restrict__ hidden, int N) {
    int g = blockIdx.x;
    int d = threadIdx.x;
    int lo = lb(batch, N, g);
    int hi = lb(batch, N, g + 1);
    float mx = -INFINITY, sm = 0.0f;
    for (int i = lo; i < hi; ++i) {
        float v = h[(size_t)i * D + d];
        mx = fmaxf(mx, v);
        sm += v;
    }
    float mean = sm / (float)(hi - lo);
    hidden[(size_t)g * (2 * D) + d] = mx;
    hidden[(size_t)g * (2 * D) + D + d] = mean;

    float p = mx * Wout[d] + mean * Wout[D + d];
    __shared__ float red[256];
    red[d] = p;
    __syncthreads();
    for (int s = 128; s > 0; s >>= 1) {
        if (d < s) red[d] += red[d + s];
        __syncthreads();
    }
    if (d == 0) out[g] = red[0] + bout[0];
}

// ----------------------------------------------------------------
extern "C" void kernel_launch(void* const* d_in, const int* in_sizes, int n_in,
                              void* d_out, int out_size, void* d_ws, size_t ws_size,
                              hipStream_t stream) {
    const float* x          = (const float*)d_in[0];
    const int*   edge_index = (const int*)d_in[1];
    const int*   batch      = (const int*)d_in[2];
    const float* Wl[4] = {(const float*)d_in[4], (const float*)d_in[6],
                          (const float*)d_in[8], (const float*)d_in[10]};
    const float* bl[4] = {(const float*)d_in[5], (const float*)d_in[7],
                          (const float*)d_in[9], (const float*)d_in[11]};
    const float* gl[4]  = {(const float*)d_in[12], (const float*)d_in[14],
                           (const float*)d_in[16], (const float*)d_in[18]};
    const float* bel[4] = {(const float*)d_in[13], (const float*)d_in[15],
                           (const float*)d_in[17], (const float*)d_in[19]};
    const float* Wout = (const float*)d_in[20];
    const float* bout = (const float*)d_in[21];

    const int N = in_sizes[0] / 64;       // 50000
    const int E = in_sizes[1] / 2;        // 800000
    const int B = out_size / (1 + 2 * D); // 1000

    const int* srcv = edge_index;
    const int* dstv = edge_index + E;

    // workspace carve-up
    float* P1      = (float*)d_ws;              // [N,D] fp32 agg / final h
    f16*   hw_h    = (f16*)(P1 + (size_t)N * D);// [N,D] f16 GEMM out (gather input)
    f16*   hh      = hw_h + (size_t)N * D;      // [N,D] f16 activations (GEMM input)
    f16*   xh      = hh + (size_t)N * D;        // [N,64] f16 cast of x
    f16*   Wt      = xh + (size_t)N * 64;       // [256,256] f16 transposed weights
    float* dinv    = (float*)(Wt + 256 * 256);  // [N]
    float* sums    = dinv + N;                  // [D]
    float* sumsq   = sums + D;                  // [D]
    float* coef    = sumsq + D;                 // [E]
    int*   cnt     = (int*)(coef + E);          // [N]
    int*   row_ptr = cnt + N;                   // [N+1]
    int*   cursor  = row_ptr + N + 1;           // [N]
    int*   col     = cursor + N;                // [E]
    int*   partial = col + E;                   // [SCAN_NB]

    float* out_p    = (float*)d_out;            // [B]
    float* hidden_p = out_p + B;                // [B, 512]

    // ---- CSR build (once per call)
    hipMemsetAsync(cnt, 0, (size_t)N * sizeof(int), stream);
    k_count<<<(E + 255) / 256, 256, 0, stream>>>(dstv, cnt, E);
    k_dinv<<<(N + 255) / 256, 256, 0, stream>>>(cnt, dinv, N);
    const int C = (N + SCAN_NB - 1) / SCAN_NB;
    k_scan_part<<<SCAN_NB, 256, 0, stream>>>(cnt, row_ptr, partial, N, C);
    k_scan_off<<<1, 256, 0, stream>>>(partial);
    k_scan_add<<<(N + 1 + 255) / 256, 256, 0, stream>>>(row_ptr, cursor, partial, N, C, E);
    k_fill<<<(E + 255) / 256, 256, 0, stream>>>(srcv, dstv, dinv, cursor, col, coef, E);

    // x -> f16
    k_cast<<<(N * 64 / 4 + 255) / 256, 256, 0, stream>>>(x, xh, N * 64 / 4);

    const f16* hcur = xh;
    int K = 64;
    for (int l = 0; l < 4; ++l) {
        k_prep_w<<<K, 256, 0, stream>>>(Wl[l], Wt, K);
        dim3 gg((N + 63) / 64, 4);
        k_gemm<<<gg, 256, 0, stream>>>(hcur, Wt, hw_h, N, K);
        hipMemsetAsync(sums, 0, 2 * D * sizeof(float), stream);
        k_gather<<<2048, 256, 0, stream>>>(row_ptr, col, coef, hw_h, dinv, bl[l],
                                           P1, sums, sumsq, N);
        k_bn_tanh<<<((N * D / 4) + 255) / 256, 256, 0, stream>>>(
            P1, sums, sumsq, gl[l], bel[l], 1.0f / (float)N, hh, N * D / 4, l == 3);
        hcur = hh;
        K = D;
    }

    k_pool<<<B, 256, 0, stream>>>(P1, batch, Wout, bout, out_p, hidden_p, N);
}